// Round 1
// baseline (1028.328 us; speedup 1.0000x reference)
//
#include <hip/hip_runtime.h>

#define T_TOK 32768
#define HDIM  512
#define IDIM  1024
#define NEXP  8
#define BM    64
#define KI    128

typedef float    f32x4 __attribute__((ext_vector_type(4)));
typedef _Float16 f16x8 __attribute__((ext_vector_type(8)));

// ---------------------------------------------------------------------------
// Router: logits = x @ rw + rb ; top-2 ; softmax over the 2 ; bucket append.
// Block = 64 tokens, 256 threads. Thread (tl, q) accumulates h in q's quarter.
// ---------------------------------------------------------------------------
__global__ __launch_bounds__(256) void router_kernel(
    const float* __restrict__ x, const float* __restrict__ rw,
    const float* __restrict__ rb, int* __restrict__ cnt,
    int* __restrict__ btok, float* __restrict__ bw)
{
    __shared__ float Wl[HDIM * NEXP];      // 16 KB
    __shared__ float xc[64 * 133];         // 34 KB, pitch 133 kills conflicts
    __shared__ float part[4 * 64 * 8];     // 8 KB

    const int tid = threadIdx.x;
    const int t0  = blockIdx.x * 64;

    for (int j = tid; j < HDIM * NEXP / 4; j += 256)
        ((float4*)Wl)[j] = ((const float4*)rw)[j];

    const int tl = tid & 63;
    const int q  = tid >> 6;

    float acc[8];
#pragma unroll
    for (int e = 0; e < 8; ++e) acc[e] = 0.f;

    for (int hc = 0; hc < 4; ++hc) {
        __syncthreads();
        for (int j = tid; j < 64 * 128 / 4; j += 256) {
            int row = j >> 5;
            int col = (j & 31) * 4;
            float4 v = *(const float4*)(x + (size_t)(t0 + row) * HDIM + hc * 128 + col);
            float* d = &xc[row * 133 + col];
            d[0] = v.x; d[1] = v.y; d[2] = v.z; d[3] = v.w;
        }
        __syncthreads();
#pragma unroll
        for (int hh = 0; hh < 32; ++hh) {
            int h = q * 32 + hh;
            float xv = xc[tl * 133 + h];
            const float* wrow = &Wl[(hc * 128 + h) * 8];
#pragma unroll
            for (int e = 0; e < 8; ++e) acc[e] += xv * wrow[e];
        }
    }
#pragma unroll
    for (int e = 0; e < 8; ++e) part[(q * 64 + tl) * 8 + e] = acc[e];
    __syncthreads();

    if (tid < 64) {
        float lg[8];
#pragma unroll
        for (int e = 0; e < 8; ++e)
            lg[e] = part[(0 * 64 + tid) * 8 + e] + part[(1 * 64 + tid) * 8 + e] +
                    part[(2 * 64 + tid) * 8 + e] + part[(3 * 64 + tid) * 8 + e] + rb[e];
        // top-2 with jax.lax.top_k tie semantics (lowest index wins ties)
        int e0 = 0;
#pragma unroll
        for (int e = 1; e < 8; ++e) if (lg[e] > lg[e0]) e0 = e;
        int e1 = (e0 == 0) ? 1 : 0;
#pragma unroll
        for (int e = 0; e < 8; ++e) if (e != e0 && lg[e] > lg[e1]) e1 = e;
        float z  = __expf(lg[e1] - lg[e0]);   // <= 1, no overflow
        float w0 = 1.f / (1.f + z);
        float w1 = z * w0;
        int t = t0 + tid;
        int s0 = atomicAdd(&cnt[e0], 1);
        btok[e0 * T_TOK + s0] = t;  bw[e0 * T_TOK + s0] = w0;
        int s1 = atomicAdd(&cnt[e1], 1);
        btok[e1 * T_TOK + s1] = t;  bw[e1 * T_TOK + s1] = w1;
    }
}

// ---------------------------------------------------------------------------
// Transpose + fp32->fp16 convert: src [E][R][C] f32 -> dst [E][C][R] f16
// ---------------------------------------------------------------------------
template <int R, int C>
__global__ __launch_bounds__(256) void transpose_cvt(
    const float* __restrict__ src, _Float16* __restrict__ dst)
{
    __shared__ float tile[32][33];
    const int e  = blockIdx.z;
    const int rb = blockIdx.y * 32, cb = blockIdx.x * 32;
    const int tx = threadIdx.x & 31, ty = threadIdx.x >> 5;  // ty in 0..7
#pragma unroll
    for (int j = 0; j < 32; j += 8)
        tile[ty + j][tx] = src[((size_t)e * R + rb + ty + j) * C + cb + tx];
    __syncthreads();
#pragma unroll
    for (int j = 0; j < 32; j += 8)
        dst[((size_t)e * C + cb + ty + j) * R + rb + tx] = (_Float16)tile[tx][ty + j];
}

// ---------------------------------------------------------------------------
// Fused expert kernel. Block = (expert e, 64 bucket rows), 512 threads (8 waves).
// A (x rows) staged fp16 in swizzled LDS. Per 128-wide I-chunk:
//   phase1: gate/up = A @ Wgu_t (wave -> 16 cols of gate + 16 of up)
//   act    = (up+1)*quick_gelu(gate) -> swizzled LDS fp16
//   phase2: accO[64 x 64-per-wave] += act @ Wd_t
// Epilogue: atomicAdd( w * (accO + bd) ) into out rows.
// MFMA 16x16x32 f16 layouts: A row = lane&15, k = (lane>>4)*8+j ;
// B n = lane&15, k = (lane>>4)*8+j ; D col = lane&15, row = (lane>>4)*4+r.
// ---------------------------------------------------------------------------
__global__ __launch_bounds__(512) void moe_kernel(
    const float* __restrict__ x,
    const _Float16* __restrict__ wgu_t,   // [E][2I][H]
    const float* __restrict__ bgu,        // [E][2I]
    const _Float16* __restrict__ wd_t,    // [E][H][I]
    const float* __restrict__ bd,         // [E][H]
    const int* __restrict__ cnt,
    const int* __restrict__ btok,
    const float* __restrict__ bw,
    float* __restrict__ out)
{
    const int e   = blockIdx.y;
    const int n_e = cnt[e];
    const int m0  = blockIdx.x * BM;
    if (m0 >= n_e) return;

    __shared__ __align__(16) _Float16 A[BM * HDIM];    // 64 KB, XOR-swizzled
    __shared__ __align__(16) _Float16 ACT[BM * KI];    // 16 KB, XOR-swizzled
    __shared__ int   s_tok[BM];
    __shared__ float s_w[BM];

    const int tid  = threadIdx.x;
    const int lane = tid & 63;
    const int wv   = tid >> 6;            // 0..7
    const int bn   = lane & 15;
    const int bk   = (lane >> 4) * 8;

    if (tid < BM) {
        int idx = m0 + tid;
        if (idx < n_e) { s_tok[tid] = btok[e * T_TOK + idx]; s_w[tid] = bw[e * T_TOK + idx]; }
        else           { s_tok[tid] = -1;                    s_w[tid] = 0.f; }
    }
    __syncthreads();

    // ---- gather x rows -> fp16 swizzled LDS (8 threads per row, 32B runs) ----
    {
        const int r  = tid >> 3;
        const int tk = s_tok[r];
#pragma unroll
        for (int j = 0; j < 8; ++j) {
            const int c = ((tid & 7) + j * 8) * 8;     // 8 floats per step
            float4 f0, f1;
            if (tk >= 0) {
                const float4* p = (const float4*)(x + (size_t)tk * HDIM + c);
                f0 = p[0]; f1 = p[1];
            } else { f0 = make_float4(0, 0, 0, 0); f1 = f0; }
            f16x8 h;
            h[0] = (_Float16)f0.x; h[1] = (_Float16)f0.y;
            h[2] = (_Float16)f0.z; h[3] = (_Float16)f0.w;
            h[4] = (_Float16)f1.x; h[5] = (_Float16)f1.y;
            h[6] = (_Float16)f1.z; h[7] = (_Float16)f1.w;
            int byte = r * 1024 + c * 2;  byte ^= (r & 7) << 4;
            *(f16x8*)((char*)A + byte) = h;
        }
    }
    __syncthreads();

    f32x4 accO[4][4];
#pragma unroll
    for (int mt = 0; mt < 4; ++mt)
#pragma unroll
        for (int nt = 0; nt < 4; ++nt)
#pragma unroll
            for (int r = 0; r < 4; ++r) accO[mt][nt][r] = 0.f;

    for (int ic = 0; ic < IDIM / KI; ++ic) {
        // ------------------ phase 1: gate & up ------------------
        f32x4 accG[4], accU[4];
#pragma unroll
        for (int mt = 0; mt < 4; ++mt)
#pragma unroll
            for (int r = 0; r < 4; ++r) { accG[mt][r] = 0.f; accU[mt][r] = 0.f; }

        const _Float16* bg = wgu_t + ((size_t)(e * 2 * IDIM) + ic * KI + wv * 16 + bn) * HDIM;
        const _Float16* bu = bg + (size_t)IDIM * HDIM;

        for (int ks = 0; ks < 16; ++ks) {
            const int k0 = ks * 32 + bk;
            f16x8 bgf = *(const f16x8*)(bg + k0);
            f16x8 buf = *(const f16x8*)(bu + k0);
#pragma unroll
            for (int mt = 0; mt < 4; ++mt) {
                const int m = mt * 16 + bn;
                int byte = m * 1024 + k0 * 2;  byte ^= (m & 7) << 4;
                f16x8 af = *(const f16x8*)((const char*)A + byte);
                accG[mt] = __builtin_amdgcn_mfma_f32_16x16x32_f16(af, bgf, accG[mt], 0, 0, 0);
                accU[mt] = __builtin_amdgcn_mfma_f32_16x16x32_f16(af, buf, accU[mt], 0, 0, 0);
            }
        }
        // bias + quick_gelu, store act chunk
        const int   gcol = ic * KI + wv * 16 + bn;
        const float bgv  = bgu[e * 2 * IDIM + gcol];
        const float buv  = bgu[e * 2 * IDIM + IDIM + gcol];
#pragma unroll
        for (int mt = 0; mt < 4; ++mt) {
#pragma unroll
            for (int r = 0; r < 4; ++r) {
                float g = accG[mt][r] + bgv;
                float u = accU[mt][r] + buv;
                float a = (u + 1.f) * g / (1.f + __expf(-1.702f * g));
                const int row = mt * 16 + ((lane >> 4) << 2) + r;
                const int col = wv * 16 + bn;
                int byte = row * 256 + col * 2;  byte ^= (row & 7) << 4;
                *(_Float16*)((char*)ACT + byte) = (_Float16)a;
            }
        }
        __syncthreads();

        // ------------------ phase 2: down-proj accumulate ------------------
        const _Float16* bdp = wd_t + ((size_t)(e * HDIM) + wv * 64) * IDIM;
#pragma unroll
        for (int ks = 0; ks < 4; ++ks) {
            const int kl = ks * 32 + bk;
            const int kg = ic * KI + kl;
            f16x8 bf[4];
#pragma unroll
            for (int nt = 0; nt < 4; ++nt)
                bf[nt] = *(const f16x8*)(bdp + (size_t)(nt * 16 + bn) * IDIM + kg);
#pragma unroll
            for (int mt = 0; mt < 4; ++mt) {
                const int m = mt * 16 + bn;
                int byte = m * 256 + kl * 2;  byte ^= (m & 7) << 4;
                f16x8 af = *(const f16x8*)((const char*)ACT + byte);
#pragma unroll
                for (int nt = 0; nt < 4; ++nt)
                    accO[mt][nt] = __builtin_amdgcn_mfma_f32_16x16x32_f16(af, bf[nt], accO[mt][nt], 0, 0, 0);
            }
        }
        __syncthreads();
    }

    // ------------------ epilogue: weighted atomic scatter ------------------
    float bdv[4];
#pragma unroll
    for (int nt = 0; nt < 4; ++nt) bdv[nt] = bd[e * HDIM + wv * 64 + nt * 16 + bn];
#pragma unroll
    for (int mt = 0; mt < 4; ++mt) {
#pragma unroll
        for (int r = 0; r < 4; ++r) {
            const int m  = mt * 16 + ((lane >> 4) << 2) + r;
            const int tk = s_tok[m];
            if (tk < 0) continue;
            const float wgt = s_w[m];
            float* orow = out + (size_t)tk * HDIM + wv * 64 + bn;
#pragma unroll
            for (int nt = 0; nt < 4; ++nt)
                atomicAdd(orow + nt * 16, (accO[mt][nt][r] + bdv[nt]) * wgt);
        }
    }
}

// ---------------------------------------------------------------------------
extern "C" void kernel_launch(void* const* d_in, const int* in_sizes, int n_in,
                              void* d_out, int out_size, void* d_ws, size_t ws_size,
                              hipStream_t stream)
{
    const float* x   = (const float*)d_in[0];
    const float* rw  = (const float*)d_in[1];
    const float* rb  = (const float*)d_in[2];
    const float* wgu = (const float*)d_in[3];
    const float* bgu = (const float*)d_in[4];
    const float* wd  = (const float*)d_in[5];
    const float* bd  = (const float*)d_in[6];
    float* out = (float*)d_out;

    char* ws = (char*)d_ws;
    size_t o = 0;
    int*   cnt  = (int*)(ws + o);   o += 256;
    int*   btok = (int*)(ws + o);   o += (size_t)NEXP * T_TOK * 4;
    float* bwp  = (float*)(ws + o); o += (size_t)NEXP * T_TOK * 4;
    _Float16* wgu_t = (_Float16*)(ws + o); o += (size_t)NEXP * 2 * IDIM * HDIM * 2;
    _Float16* wd_t  = (_Float16*)(ws + o); o += (size_t)NEXP * HDIM * IDIM * 2;
    // total ~26.2 MB of workspace

    hipMemsetAsync(cnt, 0, 256, stream);
    hipMemsetAsync(out, 0, (size_t)T_TOK * HDIM * 4, stream);

    transpose_cvt<HDIM, 2 * IDIM><<<dim3(2 * IDIM / 32, HDIM / 32, NEXP), 256, 0, stream>>>(wgu, wgu_t);
    transpose_cvt<IDIM, HDIM><<<dim3(HDIM / 32, IDIM / 32, NEXP), 256, 0, stream>>>(wd, wd_t);
    router_kernel<<<T_TOK / 64, 256, 0, stream>>>(x, rw, rb, cnt, btok, bwp);
    moe_kernel<<<dim3(T_TOK / BM, NEXP), 512, 0, stream>>>(
        x, wgu_t, bgu, wd_t, bd, cnt, btok, bwp, out);
}